// Round 2
// baseline (31.516 us; speedup 1.0000x reference)
//
#include <hip/hip_runtime.h>
#include <math.h>

#define BB 32
#define LL 512
#define DD 1024
#define TT 256
#define NK 136393      // total kept (s,e) pairs per batch
#define NK_LIN 131273  // offset(502) = 502*523/2
#define S_LIN 502
#define NEG_BIG  -3.0e38f   // finite stand-in for -inf in output
#define NEG_MASK -1.0e30f   // finite stand-in for masked logits (keeps sums finite)

// ---------------- Kernel 1: logits = text @ W + b  (B*L rows, D=1024) ------
// One wave per row; lane reads 4 float4s (coalesced 1KB/instr per wave).
__global__ __launch_bounds__(256) void logits_kernel(
    const float* __restrict__ text, const float* __restrict__ W,
    const float* __restrict__ bias, float* __restrict__ logits)
{
    const int wid  = threadIdx.x >> 6;
    const int lane = threadIdx.x & 63;
    const int row  = blockIdx.x * 4 + wid;        // row = b*L + l
    const float4* t4 = (const float4*)(text + (size_t)row * DD);

    float a0 = 0.f, a1 = 0.f, a2 = 0.f;
#pragma unroll
    for (int j = 0; j < 4; ++j) {
        const int fi = lane + j * 64;             // float4 index within row
        float4 v = t4[fi];
        const float* wp = W + (size_t)fi * 12;    // (fi*4)*3
        a0 += v.x * wp[0];  a1 += v.x * wp[1];  a2 += v.x * wp[2];
        a0 += v.y * wp[3];  a1 += v.y * wp[4];  a2 += v.y * wp[5];
        a0 += v.z * wp[6];  a1 += v.z * wp[7];  a2 += v.z * wp[8];
        a0 += v.w * wp[9];  a1 += v.w * wp[10]; a2 += v.w * wp[11];
    }
#pragma unroll
    for (int off = 32; off; off >>= 1) {
        a0 += __shfl_down(a0, off);
        a1 += __shfl_down(a1, off);
        a2 += __shfl_down(a2, off);
    }
    if (lane == 0) {
        logits[(size_t)row * 3 + 0] = a0 + bias[0];
        logits[(size_t)row * 3 + 1] = a1 + bias[1];
        logits[(size_t)row * 3 + 2] = a2 + bias[2];
    }
}

// ---------------- Kernel 2: per-batch cumsum + ts/te scatter ---------------
__global__ __launch_bounds__(512) void scan_kernel(
    const float* __restrict__ logits, const int* __restrict__ mask,
    const int* __restrict__ tmap,
    float* __restrict__ slp, float* __restrict__ elp,
    float* __restrict__ csum, float* __restrict__ cprev,
    int* __restrict__ fs, int* __restrict__ fe)
{
    const int b = blockIdx.x;
    const int l = threadIdx.x;
    __shared__ float sc[LL];
    __shared__ int tsl[LL];
    __shared__ int tel[LL];

    tsl[l] = 0; tel[l] = 0;

    const int idx = b * LL + l;
    const int m = mask[idx];
    const float l0 = logits[(size_t)idx * 3 + 0];
    const float l1 = logits[(size_t)idx * 3 + 1];
    const float l2 = logits[(size_t)idx * 3 + 2];
    const float s_lp = (m == 1) ? l0 : NEG_MASK;
    const float e_lp = (m == 1) ? l1 : NEG_MASK;
    const float m_lp = (m == 1) ? l2 : NEG_MASK;
    sc[l] = m_lp;
    __syncthreads();

    if (l < TT) {
        int s0 = tmap[((size_t)b * TT + l) * 2 + 0];
        int e0 = tmap[((size_t)b * TT + l) * 2 + 1] - 1;
        s0 = min(max(s0, 0), LL - 1);
        e0 = min(max(e0, 0), LL - 1);
        tsl[s0] = 1;           // benign write race: all write 1
        tel[e0] = 1;
    }

    // Hillis-Steele inclusive scan over 512 elements
    for (int off = 1; off < LL; off <<= 1) {
        float v = 0.f;
        if (l >= off) v = sc[l - off];
        __syncthreads();
        if (l >= off) sc[l] += v;
        __syncthreads();
    }

    const float cs = sc[l];
    const float cp = (l == 0) ? 0.f : sc[l - 1];

    slp[idx]   = s_lp;
    elp[idx]   = e_lp;
    csum[idx]  = cs;
    cprev[idx] = cp;
    fs[idx] = (l != 0 && m == 1 && tsl[l]) ? 1 : 0;  // mask[s] & ts[s]
    fe[idx] = (l != 0 && tel[l]) ? 1 : 0;            // te[e]
}

// ---------------- Kernel 3: emit kept pairs (scores + bounds) --------------
// offset(s) = s*(s+21)/2 for s<=502 ; linear (stride 512) after.
__global__ __launch_bounds__(256) void out_kernel(
    const float* __restrict__ slp, const float* __restrict__ elp,
    const float* __restrict__ csum, const float* __restrict__ cprev,
    const int* __restrict__ fs, const int* __restrict__ fe,
    float* __restrict__ out)
{
    const int k = blockIdx.x * 256 + threadIdx.x;
    const int b = blockIdx.y;
    if (k >= NK) return;

    int s, e;
    if (k >= NK_LIN) {
        const int r = k - NK_LIN;
        s = S_LIN + (r >> 9);
        e = r & 511;
    } else {
        float f = sqrtf(8.0f * (float)k + 441.0f);
        s = (int)((f - 21.0f) * 0.5f);
        if (s < 0) s = 0;
        if (s > 501) s = 501;
        while ((s + 1) * (s + 22) / 2 <= k) ++s;   // offset(s+1) <= k
        while (s * (s + 21) / 2 > k) --s;          // offset(s)   >  k
        e = k - s * (s + 21) / 2;
    }

    const int is = b * LL + s;
    const int ie = b * LL + e;
    const bool valid = (s <= e) && fs[is] && fe[ie];
    const float score = valid
        ? ((slp[is] + elp[ie]) + (csum[ie] - cprev[is]))
        : NEG_BIG;

    out[(size_t)b * NK + k] = score;

    float2* bptr = (float2*)(out + (size_t)BB * NK);
    bptr[(size_t)b * NK + k] = make_float2((float)s, (float)e);
}

extern "C" void kernel_launch(void* const* d_in, const int* in_sizes, int n_in,
                              void* d_out, int out_size, void* d_ws, size_t ws_size,
                              hipStream_t stream) {
    const float* text = (const float*)d_in[0];   // (B,L,D) f32
    const int*   mask = (const int*)d_in[1];     // (B,L) i32
    const int*   tmap = (const int*)d_in[2];     // (B,T,2) i32
    const float* W    = (const float*)d_in[3];   // (D,3) f32
    const float* bias = (const float*)d_in[4];   // (3,) f32
    float* out = (float*)d_out;

    float* logits = (float*)d_ws;                // B*L*3
    float* slp    = logits + (size_t)BB * LL * 3;
    float* elp    = slp    + (size_t)BB * LL;
    float* csum   = elp    + (size_t)BB * LL;
    float* cprev  = csum   + (size_t)BB * LL;
    int*   fs     = (int*)(cprev + (size_t)BB * LL);
    int*   fe     = fs + (size_t)BB * LL;

    logits_kernel<<<BB * LL / 4, 256, 0, stream>>>(text, W, bias, logits);
    scan_kernel<<<BB, 512, 0, stream>>>(logits, mask, tmap, slp, elp, csum, cprev, fs, fe);
    dim3 g3((NK + 255) / 256, BB);
    out_kernel<<<g3, 256, 0, stream>>>(slp, elp, csum, cprev, fs, fe, out);
}